// Round 10
// baseline (966.980 us; speedup 1.0000x reference)
//
#include <hip/hip_runtime.h>
#include <hip/hip_bf16.h>

#define NN 100000
#define HH 64
#define AN 92
#define NSTEP 8
#define NGRP 6250          // NN / 16, exact
#define RB 768             // reduce blocks (persistent MFMA; ~2 groups/wave)
#define CAP 32             // slots per node; P(deg>=32 | mean 8) ~ 3e-11 total

typedef float f4v __attribute__((ext_vector_type(4)));
typedef short s8v __attribute__((ext_vector_type(8)));

__device__ __forceinline__ float sigf(float x) { return 1.0f / (1.0f + __expf(-x)); }
// tanh(x) = 1 - 2/(1+e^{2x}); saturates correctly, no NaN.
__device__ __forceinline__ float tanhfast(float x) { return 1.0f - 2.0f / (1.0f + __expf(2.0f * x)); }

__device__ __forceinline__ unsigned short tobf(float x) {
    __hip_bfloat16 b = __float2bfloat16(x);   // RNE
    return __builtin_bit_cast(unsigned short, b);
}
__device__ __forceinline__ float frombf(unsigned short u) {
    return __int_as_float(((unsigned)u) << 16);
}

// ---------------------------------------------------------------------------
// R27 CHUNK LAYOUT: hb / Sb stored [8][NN][8] bf16. Chunk cg = columns
// cg*8..cg*8+7 (16 B/node, 1.6 MB/table < 4 MB per-XCD L2). k_aggrc blocks
// with cg = blockIdx&7 land on XCD cg (round-robin dispatch, m157 basis) ->
// random gathers become L2 hits; compulsory drops 102 -> 12.8 MB/step.
// Unlike R18: wave shape preserved (2 nodes/wave, 16 lines in flight).
// ---------------------------------------------------------------------------

// Packed B-fragment position for mfma_f32_16x16x32_bf16 (K=64, 2 kh):
// element B[k][r] lives at ((T*2+kh)*64 + lane)*8 + j,
// T=r>>4, kh=k>>5, lane=((k>>3)&3)*16 + (r&15), j=k&7.
__device__ __forceinline__ int packpos(int k, int r) {
    int T = r >> 4, kh = k >> 5;
    int lane = ((k >> 3) & 3) * 16 + (r & 15);
    int j = k & 7;
    return ((T * 2 + kh) * 64 + lane) * 8 + j;
}

// R22/R23: weights-only packing kernel: blocks 0..383 compute
// Wcp[t] = bf16(W_g[t] @ w_ih pack), blocks 384..431 pack Whp.
__global__ __launch_bounds__(256) void k_wcp(const float* __restrict__ Wg,
                                             const float* __restrict__ w_ih,
                                             const float* __restrict__ w_hh,
                                             unsigned short* __restrict__ Wcp,
                                             unsigned short* __restrict__ Whp) {
    __shared__ float wl[192 * 65];
    int wb = blockIdx.x;
    if (wb < 384) {
        for (int i = threadIdx.x; i < 192 * 64; i += 256) {
            int r = i >> 6, q = i & 63;
            wl[r * 65 + q] = w_ih[i];
        }
        __syncthreads();
        int gid = wb * 256 + threadIdx.x;
        int r = gid % 192;
        int k = (gid / 192) & 63;
        int t = gid / (192 * 64);
        const float* wg = Wg + t * 4096 + k * 64;
        float acc = 0.f;
#pragma unroll
        for (int q = 0; q < 64; ++q) acc = fmaf(wg[q], wl[r * 65 + q], acc);
        Wcp[t * 12288 + packpos(k, r)] = tobf(acc);
    } else {
        int gid = (wb - 384) * 256 + threadIdx.x;
        if (gid >= 192 * 64) return;
        int r = gid >> 6, k = gid & 63;
        Whp[packpos(k, r)] = tobf(w_hh[r * 64 + k]);
    }
}

// FUSED: k_reduce (blocks 0..RB-1, persistent MFMA) + k_place (blocks RB..).
// R25 reduce engine; R27: hb epilogue writes chunk layout.
__global__ __launch_bounds__(256) void k_plred(const int* __restrict__ src,
                                               const int* __restrict__ dst,
                                               int* __restrict__ cnt,
                                               int* __restrict__ srt, int E,
                                               const float* __restrict__ x,
                                               const float* __restrict__ W,
                                               const float* __restrict__ b,
                                               unsigned short* __restrict__ hb) {
    __shared__ __align__(16) unsigned short wrp[6144];   // 12 KB W_red B-pack
    __shared__ __align__(16) float xs[4][1472];          // 23 KB, per-wave x tile
    int tid = threadIdx.x;
    if (blockIdx.x >= RB) {
        // ---- place branch (R22 slot placement) ----
        int e = (blockIdx.x - RB) * 256 + tid;
        if (e < E) {
            int d = dst[e];
            int pos = atomicAdd(cnt + d, 1);
            if (pos < CAP) srt[d * CAP + pos] = src[e];
        }
        return;
    }
    // ---- reduce branch: pack W_red into LDS (3-kh packpos), once ----
    for (int i = tid; i < 96 * 64; i += 256) {
        int k = i >> 6, r = i & 63;
        float val = (k < AN) ? W[k * HH + r] : 0.f;   // zero-pad k=92..95
        int T = r >> 4, kh = k >> 5;
        int ln = ((k >> 3) & 3) * 16 + (r & 15);
        int j = k & 7;
        wrp[((T * 3 + kh) * 64 + ln) * 8 + j] = tobf(val);
    }
    __syncthreads();   // the only barrier; loop below is wave-local
    const s8v* wB = (const s8v*)wrp;
    int lane = tid & 63, wave = tid >> 6;
    int row16 = lane & 15, quad = lane >> 4;
    float bj[4];
#pragma unroll
    for (int t = 0; t < 4; ++t) bj[t] = b[t * 16 + row16];
    float4* xd = (float4*)xs[wave];
    const float* xrow = xs[wave] + row16 * AN;

    for (int g = blockIdx.x * 4 + wave; g < NGRP; g += RB * 4) {
        int n0 = g * 16;
        // stage 16x92 fp32 tile: 6 coalesced float4 loads (1 KB/instr)
        const float4* xsrc = (const float4*)(x + (size_t)n0 * AN);  // 16B-aligned (5888B groups)
#pragma unroll
        for (int i = 0; i < 5; ++i) xd[i * 64 + lane] = xsrc[i * 64 + lane];
        if (lane < 48) xd[320 + lane] = xsrc[320 + lane];
        // A-fragments from LDS (compiler orders ds_write->ds_read via lgkmcnt)
        s8v A[3];
#pragma unroll
        for (int kh = 0; kh < 3; ++kh) {
            int k0 = quad * 8 + kh * 32;
            float4 lo = *(const float4*)(xrow + k0);
            float4 hi;
            if (kh == 2 && quad == 3) hi = make_float4(0.f, 0.f, 0.f, 0.f);  // k 92..95 pad
            else hi = *(const float4*)(xrow + k0 + 4);
            s8v f;
            f[0] = (short)tobf(lo.x); f[1] = (short)tobf(lo.y);
            f[2] = (short)tobf(lo.z); f[3] = (short)tobf(lo.w);
            f[4] = (short)tobf(hi.x); f[5] = (short)tobf(hi.y);
            f[6] = (short)tobf(hi.z); f[7] = (short)tobf(hi.w);
            A[kh] = f;
        }
#pragma unroll
        for (int t = 0; t < 4; ++t) {
            f4v acc = {bj[t], bj[t], bj[t], bj[t]};
#pragma unroll
            for (int kh = 0; kh < 3; ++kh)
                acc = __builtin_amdgcn_mfma_f32_16x16x32_bf16(A[kh], wB[(t * 3 + kh) * 64 + lane], acc, 0, 0, 0);
#pragma unroll
            for (int reg = 0; reg < 4; ++reg) {
                int node = n0 + quad * 4 + reg;
                int cc = t * 16 + row16;
                hb[((size_t)(cc >> 3) * NN + node) * 8 + (cc & 7)] = tobf(acc[reg]);
            }
        }
    }
}

// R27 column-sharded aggregation. Block (nb, cg=blockIdx&7): 8 nodes, chunk
// cg only. Per wave: 2 nodes (max-over-2 tail, same as R26); per node 32
// lanes = 8 edge-slots x 4 lanes x 4 B; slot s walks edges s, s+8, ... then
// 3x shfl_xor slot-reduce. 16 lines in flight per wave via ONE load/lane.
__global__ __launch_bounds__(256) void k_aggrc(const unsigned short* __restrict__ hbc,
                                               const int* __restrict__ cnt,
                                               const int* __restrict__ srt,
                                               unsigned short* __restrict__ Sbc) {
    int cg = blockIdx.x & 7;
    int nb = blockIdx.x >> 3;
    int lane = threadIdx.x & 63;
    int wave = threadIdx.x >> 6;
    int half = lane >> 5;
    int ci = lane & 31;
    int slot = ci >> 2, q = ci & 3;
    int n = nb * 8 + wave * 2 + half;   // NN % 8 == 0: always valid
    int st = n * CAP;
    int en = st + min(cnt[n], CAP);
    const unsigned short* tab = hbc + (size_t)cg * ((size_t)NN * 8);
    float a0 = 0.f, a1 = 0.f;
    for (int j = st + slot; j < en; j += 8) {
        unsigned uu = *(const unsigned*)(tab + (size_t)srt[j] * 8 + q * 2);
        a0 += frombf((unsigned short)uu);
        a1 += frombf((unsigned short)(uu >> 16));
    }
    a0 += __shfl_xor(a0, 4, 64);  a1 += __shfl_xor(a1, 4, 64);
    a0 += __shfl_xor(a0, 8, 64);  a1 += __shfl_xor(a1, 8, 64);
    a0 += __shfl_xor(a0, 16, 64); a1 += __shfl_xor(a1, 16, 64);
    if (slot == 0) {
        unsigned o = (unsigned)tobf(a0) | ((unsigned)tobf(a1) << 16);
        *(unsigned*)(Sbc + ((size_t)cg * NN + n) * 8 + q * 2) = o;
    }
}

// MFMA GRU, chunk layout (R18-verified addressing), in-place hb (split-kernel
// semantics). Fragment loads improve: quad's 16 lanes read 256 B contiguous.
__global__ __launch_bounds__(256) void k_gruc(const unsigned short* __restrict__ Sbc,
                                              unsigned short* __restrict__ hbc,
                                              const unsigned short* __restrict__ Wcp_t,
                                              const unsigned short* __restrict__ Whp,
                                              const float* __restrict__ b_ih,
                                              const float* __restrict__ b_hh) {
    const s8v* wiB = (const s8v*)Wcp_t;   // frag index (T*2+kh)*64 + lane
    const s8v* whB = (const s8v*)Whp;

    int lane = threadIdx.x & 63;
    int wave = threadIdx.x >> 6;
    int quad = lane >> 4, nidx = lane & 15;
    int g = blockIdx.x * 4 + wave;
    if (g >= NGRP) return;

    float brz[4], bzz[4], bin[4], bhn[4];
#pragma unroll
    for (int t = 0; t < 4; ++t) {
        int c = t * 16 + nidx;
        brz[t] = b_ih[c] + b_hh[c];
        bzz[t] = b_ih[64 + c] + b_hh[64 + c];
        bin[t] = b_ih[128 + c];
        bhn[t] = b_hh[128 + c];
    }

    int n0 = g * 16;
    size_t soff = ((size_t)quad * NN + (n0 + nidx)) * 8;   // chunk quad / quad+4
    s8v aS0 = *(const s8v*)(Sbc + soff);
    s8v aS1 = *(const s8v*)(Sbc + soff + (size_t)4 * NN * 8);
    s8v aH0 = *(const s8v*)(hbc + soff);
    s8v aH1 = *(const s8v*)(hbc + soff + (size_t)4 * NN * 8);

#pragma unroll
    for (int t = 0; t < 4; ++t) {
        f4v aRZ0 = {brz[t], brz[t], brz[t], brz[t]};
        f4v aRZ1 = {bzz[t], bzz[t], bzz[t], bzz[t]};
        f4v aIN  = {bin[t], bin[t], bin[t], bin[t]};
        f4v aHN  = {bhn[t], bhn[t], bhn[t], bhn[t]};
        aRZ0 = __builtin_amdgcn_mfma_f32_16x16x32_bf16(aS0, wiB[(t * 2 + 0) * 64 + lane], aRZ0, 0, 0, 0);
        aRZ0 = __builtin_amdgcn_mfma_f32_16x16x32_bf16(aS1, wiB[(t * 2 + 1) * 64 + lane], aRZ0, 0, 0, 0);
        aRZ0 = __builtin_amdgcn_mfma_f32_16x16x32_bf16(aH0, whB[(t * 2 + 0) * 64 + lane], aRZ0, 0, 0, 0);
        aRZ0 = __builtin_amdgcn_mfma_f32_16x16x32_bf16(aH1, whB[(t * 2 + 1) * 64 + lane], aRZ0, 0, 0, 0);
        int tz = t + 4;
        aRZ1 = __builtin_amdgcn_mfma_f32_16x16x32_bf16(aS0, wiB[(tz * 2 + 0) * 64 + lane], aRZ1, 0, 0, 0);
        aRZ1 = __builtin_amdgcn_mfma_f32_16x16x32_bf16(aS1, wiB[(tz * 2 + 1) * 64 + lane], aRZ1, 0, 0, 0);
        aRZ1 = __builtin_amdgcn_mfma_f32_16x16x32_bf16(aH0, whB[(tz * 2 + 0) * 64 + lane], aRZ1, 0, 0, 0);
        aRZ1 = __builtin_amdgcn_mfma_f32_16x16x32_bf16(aH1, whB[(tz * 2 + 1) * 64 + lane], aRZ1, 0, 0, 0);
        int tn = t + 8;
        aIN = __builtin_amdgcn_mfma_f32_16x16x32_bf16(aS0, wiB[(tn * 2 + 0) * 64 + lane], aIN, 0, 0, 0);
        aIN = __builtin_amdgcn_mfma_f32_16x16x32_bf16(aS1, wiB[(tn * 2 + 1) * 64 + lane], aIN, 0, 0, 0);
        aHN = __builtin_amdgcn_mfma_f32_16x16x32_bf16(aH0, whB[(tn * 2 + 0) * 64 + lane], aHN, 0, 0, 0);
        aHN = __builtin_amdgcn_mfma_f32_16x16x32_bf16(aH1, whB[(tn * 2 + 1) * 64 + lane], aHN, 0, 0, 0);
        int c = t * 16 + nidx;
        int ch = c >> 3, cc = c & 7;
#pragma unroll
        for (int reg = 0; reg < 4; ++reg) {
            int node = n0 + quad * 4 + reg;
            float rv = sigf(aRZ0[reg]);
            float zv = sigf(aRZ1[reg]);
            float nv = tanhfast(fmaf(rv, aHN[reg], aIN[reg]));
            size_t off = ((size_t)ch * NN + node) * 8 + cc;
            float ho = frombf(hbc[off]);
            float hnew = fmaf(zv, ho - nv, nv);  // (1-z)n + z h
            hbc[off] = tobf(hnew);
        }
    }
}

// out[i] = sigmoid(dot(hb[idx[i]], W_lin) + b_lin); chunk-layout read
__global__ __launch_bounds__(256) void k_readout(const unsigned short* __restrict__ hbc,
                                                 const int* __restrict__ idx,
                                                 const float* __restrict__ Wl,
                                                 const float* __restrict__ bl,
                                                 float* __restrict__ out, int B) {
    int gid = blockIdx.x * 256 + threadIdx.x;
    int i = gid >> 6, lane = gid & 63;
    if (i >= B) return;
    int n = idx[i];
    float v = frombf(hbc[((size_t)(lane >> 3) * NN + n) * 8 + (lane & 7)]) * Wl[lane];
#pragma unroll
    for (int off = 32; off > 0; off >>= 1) v += __shfl_xor(v, off, 64);
    if (lane == 0) out[i] = sigf(v + bl[0]);
}

extern "C" void kernel_launch(void* const* d_in, const int* in_sizes, int n_in,
                              void* d_out, int out_size, void* d_ws, size_t ws_size,
                              hipStream_t stream) {
    const float* x     = (const float*)d_in[0];
    const int*   ei    = (const int*)d_in[1];
    const int*   idx   = (const int*)d_in[2];
    const float* W_red = (const float*)d_in[3];
    const float* b_red = (const float*)d_in[4];
    const float* W_g   = (const float*)d_in[5];
    const float* w_ih  = (const float*)d_in[6];
    const float* w_hh  = (const float*)d_in[7];
    const float* b_ih  = (const float*)d_in[8];
    const float* b_hh  = (const float*)d_in[9];
    const float* W_lin = (const float*)d_in[10];
    const float* b_lin = (const float*)d_in[11];
    float* out = (float*)d_out;
    const int E = in_sizes[1] / 2;
    const int B = in_sizes[2];
    const int* src = ei;
    const int* dst = ei + E;
    const int PB = (E + 255) / 256;   // place blocks

    unsigned short* hb  = (unsigned short*)d_ws;                  // 12.8 MB (bf16 h, chunk layout)
    unsigned short* Sb  = hb + (size_t)NN * HH;                   // 12.8 MB (chunk layout)
    unsigned short* Wcp = Sb + (size_t)NN * HH;                   // 196 KB
    unsigned short* Whp = Wcp + (size_t)NSTEP * 12288;            // 24 KB
    int*            cnt = (int*)(Whp + 12288);                    // 400 KB
    int*            srt = cnt + NN;                               // 12.8 MB (CAP=32)
    // total ~39 MB

    // ---- weight packing + zero counters ----
    hipMemsetAsync(cnt, 0, NN * sizeof(int), stream);
    k_wcp<<<384 + 48, 256, 0, stream>>>(W_g, w_ih, w_hh, Wcp, Whp);

    // ---- FUSED node init (persistent MFMA, first) + slot placement ----
    k_plred<<<RB + PB, 256, 0, stream>>>(src, dst, cnt, srt, E,
                                         x, W_red, b_red, hb);

    // ---- 8 propagation steps: sharded aggr + chunked GRU ----
    const int AGB = (NN / 8) * 8;   // 12500 node-blocks x 8 chunks
    for (int t = 0; t < NSTEP; ++t) {
        k_aggrc<<<AGB, 256, 0, stream>>>(hb, cnt, srt, Sb);
        k_gruc<<<1563, 256, 0, stream>>>(Sb, hb, Wcp + (size_t)t * 12288, Whp,
                                         b_ih, b_hh);
    }

    k_readout<<<(B * 64 + 255) / 256, 256, 0, stream>>>(hb, idx, W_lin, b_lin, out, B);
}

// Round 11
// 467.575 us; speedup vs baseline: 2.0681x; 2.0681x over previous
//
#include <hip/hip_runtime.h>
#include <hip/hip_bf16.h>

#define NN 100000
#define HH 64
#define AN 92
#define NSTEP 8
#define NGRP 6250          // NN / 16, exact
#define RB 768             // reduce blocks (persistent MFMA; ~2 groups/wave)
#define CAP 64             // slots per node; P(Poisson(8) > 64) ~ 1e-40/node

typedef float f4v __attribute__((ext_vector_type(4)));
typedef short s8v __attribute__((ext_vector_type(8)));

__device__ __forceinline__ float sigf(float x) { return 1.0f / (1.0f + __expf(-x)); }
// tanh(x) = 1 - 2/(1+e^{2x}); saturates correctly, no NaN.
__device__ __forceinline__ float tanhfast(float x) { return 1.0f - 2.0f / (1.0f + __expf(2.0f * x)); }

__device__ __forceinline__ unsigned short tobf(float x) {
    __hip_bfloat16 b = __float2bfloat16(x);   // RNE
    return __builtin_bit_cast(unsigned short, b);
}
__device__ __forceinline__ float frombf(unsigned short u) {
    return __int_as_float(((unsigned)u) << 16);
}

// Packed B-fragment position for mfma_f32_16x16x32_bf16 (K=64, 2 kh):
// element B[k][r] lives at ((T*2+kh)*64 + lane)*8 + j,
// T=r>>4, kh=k>>5, lane=((k>>3)&3)*16 + (r&15), j=k&7.
__device__ __forceinline__ int packpos(int k, int r) {
    int T = r >> 4, kh = k >> 5;
    int lane = ((k >> 3) & 3) * 16 + (r & 15);
    int j = k & 7;
    return ((T * 2 + kh) * 64 + lane) * 8 + j;
}

// R28 k_prep: weight packing (exact k_wcp math, LDS staging kept) + cnt
// zeroing folded into ONE dispatch (replaces hipMemsetAsync + k_wcp).
// Blocks 0..383: Wcp pack; 384..431: Whp pack; 432..529: zero cnt.
__global__ __launch_bounds__(256) void k_prep(const float* __restrict__ Wg,
                                              const float* __restrict__ w_ih,
                                              const float* __restrict__ w_hh,
                                              unsigned short* __restrict__ Wcp,
                                              unsigned short* __restrict__ Whp,
                                              int* __restrict__ cnt) {
    __shared__ float wl[192 * 65];
    int wb = blockIdx.x;
    if (wb < 384) {
        for (int i = threadIdx.x; i < 192 * 64; i += 256) {
            int r = i >> 6, q = i & 63;
            wl[r * 65 + q] = w_ih[i];
        }
        __syncthreads();
        int gid = wb * 256 + threadIdx.x;
        int r = gid % 192;
        int k = (gid / 192) & 63;
        int t = gid / (192 * 64);
        const float* wg = Wg + t * 4096 + k * 64;
        float acc = 0.f;
#pragma unroll
        for (int q = 0; q < 64; ++q) acc = fmaf(wg[q], wl[r * 65 + q], acc);
        Wcp[t * 12288 + packpos(k, r)] = tobf(acc);
    } else if (wb < 432) {
        int gid = (wb - 384) * 256 + threadIdx.x;
        if (gid >= 192 * 64) return;
        int r = gid >> 6, k = gid & 63;
        Whp[packpos(k, r)] = tobf(w_hh[r * 64 + k]);
    } else {
        int i = (wb - 432) * 1024 + threadIdx.x * 4;
        if (i + 4 <= NN) {
            int4 z; z.x = 0; z.y = 0; z.z = 0; z.w = 0;
            *(int4*)(cnt + i) = z;
        } else {
            for (int k = i; k < NN; ++k) cnt[k] = 0;
        }
    }
}

// FUSED: k_reduce (blocks 0..RB-1, persistent) + k_place (blocks RB..).
// R25 reduce: MFMA engine fed from wave-private LDS slices (coalesced
// float4 staging; no barrier in loop). Place branch = R22 slot placement.
__global__ __launch_bounds__(256) void k_plred(const int* __restrict__ src,
                                               const int* __restrict__ dst,
                                               int* __restrict__ cnt,
                                               int* __restrict__ srt, int E,
                                               const float* __restrict__ x,
                                               const float* __restrict__ W,
                                               const float* __restrict__ b,
                                               unsigned short* __restrict__ hb) {
    __shared__ __align__(16) unsigned short wrp[6144];   // 12 KB W_red B-pack
    __shared__ __align__(16) float xs[4][1472];          // 23 KB, per-wave x tile
    int tid = threadIdx.x;
    if (blockIdx.x >= RB) {
        // ---- place branch (R22 slot placement, unchanged) ----
        int e = (blockIdx.x - RB) * 256 + tid;
        if (e < E) {
            int d = dst[e];
            int pos = atomicAdd(cnt + d, 1);
            if (pos < CAP) srt[d * CAP + pos] = src[e];
        }
        return;
    }
    // ---- reduce branch: pack W_red into LDS (3-kh packpos), once ----
    for (int i = tid; i < 96 * 64; i += 256) {
        int k = i >> 6, r = i & 63;
        float val = (k < AN) ? W[k * HH + r] : 0.f;   // zero-pad k=92..95
        int T = r >> 4, kh = k >> 5;
        int ln = ((k >> 3) & 3) * 16 + (r & 15);
        int j = k & 7;
        wrp[((T * 3 + kh) * 64 + ln) * 8 + j] = tobf(val);
    }
    __syncthreads();   // the only barrier; loop below is wave-local
    const s8v* wB = (const s8v*)wrp;
    int lane = tid & 63, wave = tid >> 6;
    int row16 = lane & 15, quad = lane >> 4;
    float bj[4];
#pragma unroll
    for (int t = 0; t < 4; ++t) bj[t] = b[t * 16 + row16];
    float4* xd = (float4*)xs[wave];
    const float* xrow = xs[wave] + row16 * AN;

    for (int g = blockIdx.x * 4 + wave; g < NGRP; g += RB * 4) {
        int n0 = g * 16;
        // stage 16x92 fp32 tile: 6 coalesced float4 loads (1 KB/instr)
        const float4* xsrc = (const float4*)(x + (size_t)n0 * AN);  // 16B-aligned (5888B groups)
#pragma unroll
        for (int i = 0; i < 5; ++i) xd[i * 64 + lane] = xsrc[i * 64 + lane];
        if (lane < 48) xd[320 + lane] = xsrc[320 + lane];
        // A-fragments from LDS (compiler orders ds_write->ds_read via lgkmcnt)
        s8v A[3];
#pragma unroll
        for (int kh = 0; kh < 3; ++kh) {
            int k0 = quad * 8 + kh * 32;
            float4 lo = *(const float4*)(xrow + k0);
            float4 hi;
            if (kh == 2 && quad == 3) hi = make_float4(0.f, 0.f, 0.f, 0.f);  // k 92..95 pad
            else hi = *(const float4*)(xrow + k0 + 4);
            s8v f;
            f[0] = (short)tobf(lo.x); f[1] = (short)tobf(lo.y);
            f[2] = (short)tobf(lo.z); f[3] = (short)tobf(lo.w);
            f[4] = (short)tobf(hi.x); f[5] = (short)tobf(hi.y);
            f[6] = (short)tobf(hi.z); f[7] = (short)tobf(hi.w);
            A[kh] = f;
        }
#pragma unroll
        for (int t = 0; t < 4; ++t) {
            f4v acc = {bj[t], bj[t], bj[t], bj[t]};
#pragma unroll
            for (int kh = 0; kh < 3; ++kh)
                acc = __builtin_amdgcn_mfma_f32_16x16x32_bf16(A[kh], wB[(t * 3 + kh) * 64 + lane], acc, 0, 0, 0);
#pragma unroll
            for (int reg = 0; reg < 4; ++reg) {
                int node = n0 + quad * 4 + reg;
                hb[(size_t)node * HH + t * 16 + row16] = tobf(acc[reg]);
            }
        }
    }
}

// R26/R28 FUSED step: aggregation + GRU, one block per 16-node group, 512 thr.
// Each of the 8 waves handles ONE node-pair (50K-wave MLP preserved — the
// R19 lesson), then one barrier, then waves 0-3 run one t-tile of the GRU.
// R28: uint2 (8 B/lane) gathers — 16 lanes/row, 2 rows per load instr per
// half-wave -> 32 lines in flight per wave (2x R26) at half the instruction
// count. Same line traffic; byte-identical LDS tile layout.
// hb double-buffered (read hbo / write hbn) == split-kernel semantics.
__global__ __launch_bounds__(512) void k_step(const unsigned short* __restrict__ hbo,
                                              unsigned short* __restrict__ hbn,
                                              const int* __restrict__ cnt,
                                              const int* __restrict__ srt,
                                              const unsigned short* __restrict__ Wcp_t,
                                              const unsigned short* __restrict__ Whp,
                                              const float* __restrict__ b_ih,
                                              const float* __restrict__ b_hh) {
    __shared__ __align__(16) unsigned char sb[2048];   // 16x64 bf16, XOR-swizzled
    int tid = threadIdx.x;
    int lane = tid & 63, wave = tid >> 6;
    int n0 = blockIdx.x * 16;

    // ---- aggr phase: one node-pair per wave; uint2 gathers ----
    {
        int half = lane >> 5;
        int ci = lane & 31;
        int sub = ci >> 4;        // edge parity within the batch
        int col8 = ci & 15;       // which 8-byte chunk of the 128-B row
        int n = n0 + wave * 2 + half;
        int st = n * CAP;
        int en = st + min(cnt[n], CAP);
        float a0 = 0.f, a1 = 0.f, a2 = 0.f, a3 = 0.f;
        for (int j = st; j < en; j += 16) {
            uint2 u[8];
#pragma unroll
            for (int i = 0; i < 8; ++i) {
                int jj = j + sub + i * 2;
                int sidx = srt[min(jj, en - 1)];          // clamped: always valid
                uint2 uu = *(const uint2*)(hbo + (size_t)sidx * HH + col8 * 4);
                unsigned m = (jj < en) ? 0xffffffffu : 0u;
                u[i].x = uu.x & m;
                u[i].y = uu.y & m;
            }
#pragma unroll
            for (int i = 0; i < 8; ++i) {
                a0 += frombf((unsigned short)u[i].x);
                a1 += frombf((unsigned short)(u[i].x >> 16));
                a2 += frombf((unsigned short)u[i].y);
                a3 += frombf((unsigned short)(u[i].y >> 16));
            }
        }
        a0 += __shfl_xor(a0, 16, 64);
        a1 += __shfl_xor(a1, 16, 64);
        a2 += __shfl_xor(a2, 16, 64);
        a3 += __shfl_xor(a3, 16, 64);
        if (sub == 0) {
            unsigned o0 = (unsigned)tobf(a0) | ((unsigned)tobf(a1) << 16);
            unsigned o1 = (unsigned)tobf(a2) | ((unsigned)tobf(a3) << 16);
            int row = wave * 2 + half;
            int cb = (row * 128 + col8 * 8) ^ ((row & 7) << 4);
            uint2 ov; ov.x = o0; ov.y = o1;
            *(uint2*)(&sb[cb]) = ov;
        }
    }
    __syncthreads();
    if (wave >= 4) return;

    // ---- gru phase: wave w handles t = w (cols t*16..t*16+15) ----
    const s8v* wiB = (const s8v*)Wcp_t;   // frag index (T*2+kh)*64 + lane
    const s8v* whB = (const s8v*)Whp;
    int quad = lane >> 4, nidx = lane & 15;
    int t = wave;
    int c = t * 16 + nidx;
    float brz = b_ih[c] + b_hh[c];
    float bzz = b_ih[64 + c] + b_hh[64 + c];
    float bin = b_ih[128 + c];
    float bhn = b_hh[128 + c];

    int rb0 = (nidx * 128 + quad * 16) ^ ((nidx & 7) << 4);
    int rb1 = (nidx * 128 + 64 + quad * 16) ^ ((nidx & 7) << 4);
    s8v aS0 = *(const s8v*)(&sb[rb0]);
    s8v aS1 = *(const s8v*)(&sb[rb1]);
    size_t rowoff = (size_t)(n0 + nidx) * HH + quad * 8;
    s8v aH0 = *(const s8v*)(hbo + rowoff);
    s8v aH1 = *(const s8v*)(hbo + rowoff + 32);

    f4v aRZ0 = {brz, brz, brz, brz};
    f4v aRZ1 = {bzz, bzz, bzz, bzz};
    f4v aIN  = {bin, bin, bin, bin};
    f4v aHN  = {bhn, bhn, bhn, bhn};
    aRZ0 = __builtin_amdgcn_mfma_f32_16x16x32_bf16(aS0, wiB[(t * 2 + 0) * 64 + lane], aRZ0, 0, 0, 0);
    aRZ0 = __builtin_amdgcn_mfma_f32_16x16x32_bf16(aS1, wiB[(t * 2 + 1) * 64 + lane], aRZ0, 0, 0, 0);
    aRZ0 = __builtin_amdgcn_mfma_f32_16x16x32_bf16(aH0, whB[(t * 2 + 0) * 64 + lane], aRZ0, 0, 0, 0);
    aRZ0 = __builtin_amdgcn_mfma_f32_16x16x32_bf16(aH1, whB[(t * 2 + 1) * 64 + lane], aRZ0, 0, 0, 0);
    int tz = t + 4;
    aRZ1 = __builtin_amdgcn_mfma_f32_16x16x32_bf16(aS0, wiB[(tz * 2 + 0) * 64 + lane], aRZ1, 0, 0, 0);
    aRZ1 = __builtin_amdgcn_mfma_f32_16x16x32_bf16(aS1, wiB[(tz * 2 + 1) * 64 + lane], aRZ1, 0, 0, 0);
    aRZ1 = __builtin_amdgcn_mfma_f32_16x16x32_bf16(aH0, whB[(tz * 2 + 0) * 64 + lane], aRZ1, 0, 0, 0);
    aRZ1 = __builtin_amdgcn_mfma_f32_16x16x32_bf16(aH1, whB[(tz * 2 + 1) * 64 + lane], aRZ1, 0, 0, 0);
    int tn = t + 8;
    aIN = __builtin_amdgcn_mfma_f32_16x16x32_bf16(aS0, wiB[(tn * 2 + 0) * 64 + lane], aIN, 0, 0, 0);
    aIN = __builtin_amdgcn_mfma_f32_16x16x32_bf16(aS1, wiB[(tn * 2 + 1) * 64 + lane], aIN, 0, 0, 0);
    aHN = __builtin_amdgcn_mfma_f32_16x16x32_bf16(aH0, whB[(tn * 2 + 0) * 64 + lane], aHN, 0, 0, 0);
    aHN = __builtin_amdgcn_mfma_f32_16x16x32_bf16(aH1, whB[(tn * 2 + 1) * 64 + lane], aHN, 0, 0, 0);

#pragma unroll
    for (int reg = 0; reg < 4; ++reg) {
        int node = n0 + quad * 4 + reg;
        float rv = sigf(aRZ0[reg]);
        float zv = sigf(aRZ1[reg]);
        float nv = tanhfast(fmaf(rv, aHN[reg], aIN[reg]));
        size_t off = (size_t)node * HH + c;
        float ho = frombf(hbo[off]);         // OLD state (dbuf), same as split
        float hnew = fmaf(zv, ho - nv, nv);  // (1-z)n + z h
        hbn[off] = tobf(hnew);
    }
}

// out[i] = sigmoid(dot(hb[idx[i]], W_lin) + b_lin)
__global__ __launch_bounds__(256) void k_readout(const unsigned short* __restrict__ hb,
                                                 const int* __restrict__ idx,
                                                 const float* __restrict__ Wl,
                                                 const float* __restrict__ bl,
                                                 float* __restrict__ out, int B) {
    int gid = blockIdx.x * 256 + threadIdx.x;
    int i = gid >> 6, lane = gid & 63;
    if (i >= B) return;
    int n = idx[i];
    float v = frombf(hb[(size_t)n * HH + lane]) * Wl[lane];
#pragma unroll
    for (int off = 32; off > 0; off >>= 1) v += __shfl_xor(v, off, 64);
    if (lane == 0) out[i] = sigf(v + bl[0]);
}

extern "C" void kernel_launch(void* const* d_in, const int* in_sizes, int n_in,
                              void* d_out, int out_size, void* d_ws, size_t ws_size,
                              hipStream_t stream) {
    const float* x     = (const float*)d_in[0];
    const int*   ei    = (const int*)d_in[1];
    const int*   idx   = (const int*)d_in[2];
    const float* W_red = (const float*)d_in[3];
    const float* b_red = (const float*)d_in[4];
    const float* W_g   = (const float*)d_in[5];
    const float* w_ih  = (const float*)d_in[6];
    const float* w_hh  = (const float*)d_in[7];
    const float* b_ih  = (const float*)d_in[8];
    const float* b_hh  = (const float*)d_in[9];
    const float* W_lin = (const float*)d_in[10];
    const float* b_lin = (const float*)d_in[11];
    float* out = (float*)d_out;
    const int E = in_sizes[1] / 2;
    const int B = in_sizes[2];
    const int* src = ei;
    const int* dst = ei + E;
    const int PB = (E + 255) / 256;   // place blocks

    unsigned short* hb0 = (unsigned short*)d_ws;                  // 12.8 MB (bf16 h, dbuf A)
    unsigned short* hb1 = hb0 + (size_t)NN * HH;                  // 12.8 MB (dbuf B)
    unsigned short* Wcp = hb1 + (size_t)NN * HH;                  // 196 KB
    unsigned short* Whp = Wcp + (size_t)NSTEP * 12288;            // 24 KB
    int*            cnt = (int*)(Whp + 12288);                    // 400 KB
    int*            srt = cnt + NN;                               // 25.6 MB (CAP=64 slots/node)
    // total ~52 MB
    unsigned short* hbb[2] = {hb0, hb1};

    // ---- ONE prologue dispatch: weight packing + cnt zeroing ----
    k_prep<<<432 + 98, 256, 0, stream>>>(W_g, w_ih, w_hh, Wcp, Whp, cnt);

    // ---- FUSED node init (persistent MFMA, first) + slot placement ----
    k_plred<<<RB + PB, 256, 0, stream>>>(src, dst, cnt, srt, E,
                                         x, W_red, b_red, hb0);

    // ---- 8 propagation steps, fused aggr+GRU ----
    for (int t = 0; t < NSTEP; ++t) {
        k_step<<<NGRP, 512, 0, stream>>>(hbb[t & 1], hbb[(t + 1) & 1],
                                         cnt, srt,
                                         Wcp + (size_t)t * 12288, Whp,
                                         b_ih, b_hh);
    }

    // after 8 steps (even), final state is back in hb0
    k_readout<<<(B * 64 + 255) / 256, 256, 0, stream>>>(hb0, idx, W_lin, b_lin, out, B);
}